// Round 1
// baseline (618.883 us; speedup 1.0000x reference)
//
#include <hip/hip_runtime.h>
#include <hip/hip_bf16.h>

#define NCH 64

// ---------------------------------------------------------------------------
// Dtype detection: the reference says fp32/int64 but the harness may have
// converted to bf16/int32. Detect from bit patterns, store flags in ws.
//   flags[0] = 1 -> float tensors are fp32, 0 -> bf16
//   flags[1] = 1 -> index tensors are int64, 0 -> int32
// ---------------------------------------------------------------------------
__global__ void detect_kernel(const unsigned short* __restrict__ gprobe, int n_g16,
                              const unsigned* __restrict__ idxprobe, int n_idxw,
                              unsigned* __restrict__ flags) {
    __shared__ unsigned s_exp, s_odd;
    if (threadIdx.x == 0) { s_exp = 0u; s_odd = 0u; }
    __syncthreads();
    unsigned le = 0u, lo = 0u;
    // If G is really fp32, interpreting it as bf16 gives ~25% of elements with
    // exponent >= 0xC0 (|x| >= 2^65). Genuine bf16 N(0,1) data: none.
    for (int i = threadIdx.x; i < n_g16; i += blockDim.x) {
        unsigned ex = (unsigned)((gprobe[i] >> 7) & 0xFFu);
        if (ex >= 0xC0u) le++;
    }
    // If src is int64 (values < 2^31), every odd int32 word is 0.
    // If int32, odd words are random node ids (almost always nonzero).
    for (int i = threadIdx.x; i < n_idxw; i += blockDim.x) {
        if ((i & 1) && idxprobe[i] != 0u) lo++;
    }
    atomicAdd(&s_exp, le);
    atomicAdd(&s_odd, lo);
    __syncthreads();
    if (threadIdx.x == 0) {
        flags[0] = (s_exp > 100u) ? 1u : 0u;
        flags[1] = (s_odd < 1000u) ? 1u : 0u;
    }
}

// ---------------------------------------------------------------------------
// Zero the accumulators (ws is poisoned 0xAA before every call).
// ---------------------------------------------------------------------------
__global__ void init_kernel(float* __restrict__ sumacc, unsigned* __restrict__ maxacc,
                            unsigned* __restrict__ cnt, int n_nodes) {
    const int total = n_nodes * NCH;
    const int stride = gridDim.x * blockDim.x;
    for (int i = blockIdx.x * blockDim.x + threadIdx.x; i < total; i += stride) {
        sumacc[i] = 0.0f;
        maxacc[i] = 0u;               // 0u == 0.0f bits; enc >= 0 after relu
        if (i < n_nodes) cnt[i] = 0u;
    }
}

// ---------------------------------------------------------------------------
// Edge kernel: one wave per edge iteration. lane = output channel.
// W row per lane lives in VGPRs; rel broadcast via per-wave LDS slot.
// Aggregation via coalesced global atomics (sum: fp32 add, max: uint max).
// ---------------------------------------------------------------------------
__global__ void edge_kernel(const void* __restrict__ Gp, const void* __restrict__ Rp,
                            const void* __restrict__ srcp, const void* __restrict__ dstp,
                            const void* __restrict__ Wp, const void* __restrict__ bp,
                            float* __restrict__ sumacc, unsigned* __restrict__ maxacc,
                            unsigned* __restrict__ cnt,
                            const unsigned* __restrict__ flags, int n_edges) {
    const unsigned f32 = flags[0];
    const unsigned i64 = flags[1];
    const int lane = threadIdx.x & 63;
    const int waveInBlk = threadIdx.x >> 6;
    const int wavesPerBlk = blockDim.x >> 6;
    const int gwave = blockIdx.x * wavesPerBlk + waveInBlk;
    const int nwaves = gridDim.x * wavesPerBlk;

    __shared__ float lds[4 * NCH];
    float* slot = &lds[waveInBlk * NCH];

    // Preload W row `lane` (fp32 in VGPRs) and bias.
    float w[NCH];
    float bias;
    if (f32) {
        const float* Wf = (const float*)Wp;
        #pragma unroll
        for (int k = 0; k < NCH; ++k) w[k] = Wf[lane * NCH + k];
        bias = ((const float*)bp)[lane];
    } else {
        const __hip_bfloat16* Wh = (const __hip_bfloat16*)Wp;
        #pragma unroll
        for (int k = 0; k < NCH; ++k) w[k] = __bfloat162float(Wh[lane * NCH + k]);
        bias = __bfloat162float(((const __hip_bfloat16*)bp)[lane]);
    }

    const int niter = (n_edges + nwaves - 1) / nwaves;
    for (int it = 0; it < niter; ++it) {
        const int e = gwave + it * nwaves;
        const bool valid = (e < n_edges);
        int s = 0, d = 0;
        if (valid) {
            if (i64) {
                s = (int)((const long long*)srcp)[e];
                d = (int)((const long long*)dstp)[e];
            } else {
                s = ((const int*)srcp)[e];
                d = ((const int*)dstp)[e];
            }
            float g, r;
            if (f32) {
                g = ((const float*)Gp)[s * NCH + lane];
                r = ((const float*)Rp)[d * NCH + lane];
            } else {
                g = __bfloat162float(((const __hip_bfloat16*)Gp)[s * NCH + lane]);
                r = __bfloat162float(((const __hip_bfloat16*)Rp)[d * NCH + lane]);
            }
            slot[lane] = g - r;
        }
        __syncthreads();   // rel visible to all lanes of this block's waves
        if (valid) {
            float a0 = bias, a1 = 0.0f, a2 = 0.0f, a3 = 0.0f;
            const float4* rel4 = (const float4*)slot;
            #pragma unroll
            for (int q = 0; q < 16; ++q) {
                float4 rv = rel4[q];                 // broadcast ds_read_b128
                a0 = fmaf(rv.x, w[4 * q + 0], a0);
                a1 = fmaf(rv.y, w[4 * q + 1], a1);
                a2 = fmaf(rv.z, w[4 * q + 2], a2);
                a3 = fmaf(rv.w, w[4 * q + 3], a3);
            }
            float v = fmaxf((a0 + a1) + (a2 + a3), 0.0f);
            // coalesced: 64 consecutive dwords per wave
            atomicAdd(&sumacc[d * NCH + lane], v);
            atomicMax(&maxacc[d * NCH + lane], __float_as_uint(v));
            if (lane == 0) atomicAdd(&cnt[d], 1u);
        }
        __syncthreads();   // protect LDS slot before next iteration's write
    }
}

// ---------------------------------------------------------------------------
// Finalize: out[n, 0:64] = max (0 for empty), out[n, 64:128] = sum/max(cnt,1)
// ---------------------------------------------------------------------------
__global__ void finalize_kernel(const float* __restrict__ sumacc,
                                const unsigned* __restrict__ maxacc,
                                const unsigned* __restrict__ cnt,
                                const unsigned* __restrict__ flags,
                                void* __restrict__ outp, int n_nodes) {
    const int total = n_nodes * NCH;
    const int i = blockIdx.x * blockDim.x + threadIdx.x;
    if (i >= total) return;
    const int n = i >> 6;
    const int c = i & 63;
    const float mx = __uint_as_float(maxacc[i]);
    const float cf = (float)cnt[n];
    const float av = sumacc[i] / fmaxf(cf, 1.0f);
    if (flags[0]) {
        float* out = (float*)outp;
        out[n * 2 * NCH + c] = mx;
        out[n * 2 * NCH + NCH + c] = av;
    } else {
        __hip_bfloat16* out = (__hip_bfloat16*)outp;
        out[n * 2 * NCH + c] = __float2bfloat16(mx);
        out[n * 2 * NCH + NCH + c] = __float2bfloat16(av);
    }
}

extern "C" void kernel_launch(void* const* d_in, const int* in_sizes, int n_in,
                              void* d_out, int out_size, void* d_ws, size_t ws_size,
                              hipStream_t stream) {
    const void* G = d_in[0];
    const void* RSC = d_in[1];
    const void* src = d_in[2];
    const void* dst = d_in[3];
    const void* W = d_in[4];
    const void* b = d_in[5];

    const int n_g = in_sizes[0];           // n_nodes * 64
    const int n_nodes = n_g / NCH;
    const int n_edges = in_sizes[2];

    // ws layout: [flags 256B][sumacc N*64 f32][maxacc N*64 u32][cnt N u32]
    char* ws = (char*)d_ws;
    unsigned* flags = (unsigned*)ws;
    float* sumacc = (float*)(ws + 256);
    unsigned* maxacc = (unsigned*)(ws + 256 + (size_t)n_nodes * NCH * 4);
    unsigned* cnt = (unsigned*)(ws + 256 + (size_t)n_nodes * NCH * 8);

    const int n_g_probe = (n_g < 65536) ? n_g : 65536;
    const int n_idx_probe = (n_edges < 65536) ? n_edges : 65536;
    detect_kernel<<<1, 256, 0, stream>>>((const unsigned short*)G, n_g_probe,
                                         (const unsigned*)src, n_idx_probe, flags);

    const int total = n_nodes * NCH;
    init_kernel<<<(total + 255) / 256, 256, 0, stream>>>(sumacc, maxacc, cnt, n_nodes);

    edge_kernel<<<2048, 256, 0, stream>>>(G, RSC, src, dst, W, b,
                                          sumacc, maxacc, cnt, flags, n_edges);

    finalize_kernel<<<(total + 255) / 256, 256, 0, stream>>>(sumacc, maxacc, cnt,
                                                             flags, d_out, n_nodes);
}

// Round 2
// 375.860 us; speedup vs baseline: 1.6466x; 1.6466x over previous
//
#include <hip/hip_runtime.h>
#include <hip/hip_bf16.h>

#define NCH 64

// ---------------------------------------------------------------------------
// flags[0] = 1 -> float tensors are fp32, 0 -> bf16
// flags[1] = 1 -> index tensors are int64, 0 -> int32
// fp32 data viewed as shorts: low halves have uniform-random "bf16 exponent"
// -> ~12.5% of all shorts show exp >= 0xC0 (|x|>=2^65). Real bf16 N(0,1): none.
// int64 indices (<2^31) have all odd 32-bit words == 0; int32 ids don't.
// ---------------------------------------------------------------------------
__global__ void detect_kernel(const unsigned short* __restrict__ gp, int n16,
                              const unsigned* __restrict__ ip, int niw,
                              unsigned* __restrict__ flags) {
    __shared__ unsigned se, so;
    if (threadIdx.x == 0) { se = 0u; so = 0u; }
    __syncthreads();
    unsigned le = 0u, lo = 0u;
    for (int i = threadIdx.x; i < n16; i += blockDim.x) {
        unsigned ex = (unsigned)((gp[i] >> 7) & 0xFFu);
        if (ex >= 0xC0u) le++;
    }
    for (int i = threadIdx.x; i < niw; i += blockDim.x) {
        if ((i & 1) && ip[i] != 0u) lo++;
    }
    atomicAdd(&se, le);
    atomicAdd(&so, lo);
    __syncthreads();
    if (threadIdx.x == 0) {
        flags[0] = (se > 50u) ? 1u : 0u;
        flags[1] = (so < 50u) ? 1u : 0u;
    }
}

// Zero the degree-count array (ws is poisoned 0xAA each call).
__global__ void init_kernel(unsigned* __restrict__ cnt, int n_nodes) {
    int i = blockIdx.x * blockDim.x + threadIdx.x;
    if (i < n_nodes) cnt[i] = 0u;
}

// Histogram of dst.
__global__ void hist_kernel(const void* __restrict__ dstp, unsigned* __restrict__ cnt,
                            const unsigned* __restrict__ flags, int n_edges) {
    const unsigned i64 = flags[1];
    const int stride = gridDim.x * blockDim.x;
    for (int e = blockIdx.x * blockDim.x + threadIdx.x; e < n_edges; e += stride) {
        int d = i64 ? (int)((const long long*)dstp)[e] : ((const int*)dstp)[e];
        atomicAdd(&cnt[d], 1u);
    }
}

// Single-block exclusive scan: offs[i] = sum(cnt[0..i)).  1024 threads.
__global__ void scan_kernel(const unsigned* __restrict__ cnt, unsigned* __restrict__ offs,
                            int n_nodes) {
    __shared__ unsigned s[1024];
    const int t = threadIdx.x;
    const int L = (n_nodes + 1023) / 1024;
    const int base = t * L;
    unsigned local = 0u;
    for (int i = 0; i < L; ++i) {
        int idx = base + i;
        if (idx < n_nodes) local += cnt[idx];
    }
    s[t] = local;
    __syncthreads();
    for (int off = 1; off < 1024; off <<= 1) {
        unsigned v = (t >= off) ? s[t - off] : 0u;
        __syncthreads();
        s[t] += v;
        __syncthreads();
    }
    unsigned run = s[t] - local;            // exclusive prefix for this chunk
    for (int i = 0; i < L; ++i) {
        int idx = base + i;
        if (idx < n_nodes) { offs[idx] = run; run += cnt[idx]; }
    }
    if (t == 1023) offs[n_nodes] = s[1023];
}

// Scatter src ids into dst-sorted order. offs doubles as the cursor array:
// afterwards offs[d] == end-of-run(d) == original offs[d+1].
__global__ void scatter_kernel(const void* __restrict__ srcp, const void* __restrict__ dstp,
                               unsigned* __restrict__ offs, unsigned* __restrict__ sorted_src,
                               const unsigned* __restrict__ flags, int n_edges) {
    const unsigned i64 = flags[1];
    const int stride = gridDim.x * blockDim.x;
    for (int e = blockIdx.x * blockDim.x + threadIdx.x; e < n_edges; e += stride) {
        int s, d;
        if (i64) {
            s = (int)((const long long*)srcp)[e];
            d = (int)((const long long*)dstp)[e];
        } else {
            s = ((const int*)srcp)[e];
            d = ((const int*)dstp)[e];
        }
        unsigned pos = atomicAdd(&offs[d], 1u);
        sorted_src[pos] = (unsigned)s;
    }
}

// out[m,:] = in[m,:] @ W^T  - (subbias ? b : 0), fp32 result.
// Wave per row (grid-stride), lane = output channel, W row in VGPRs,
// row broadcast via per-wave LDS slot. Uniform iteration count -> legal barriers.
__global__ void gemm_kernel(const void* __restrict__ inp, const void* __restrict__ Wp,
                            const void* __restrict__ bp, float* __restrict__ outp,
                            const unsigned* __restrict__ flags, int n_rows, int subbias) {
    const unsigned f32 = flags[0];
    const int lane = threadIdx.x & 63;
    const int waveInBlk = threadIdx.x >> 6;
    const int wavesPerBlk = blockDim.x >> 6;
    const int gwave = blockIdx.x * wavesPerBlk + waveInBlk;
    const int nwaves = gridDim.x * wavesPerBlk;

    __shared__ float lds[4 * NCH];
    float* slot = &lds[waveInBlk * NCH];

    float w[NCH];
    float bias;
    if (f32) {
        const float* Wf = (const float*)Wp;
        #pragma unroll
        for (int k = 0; k < NCH; ++k) w[k] = Wf[lane * NCH + k];
        bias = ((const float*)bp)[lane];
    } else {
        const __hip_bfloat16* Wh = (const __hip_bfloat16*)Wp;
        #pragma unroll
        for (int k = 0; k < NCH; ++k) w[k] = __bfloat162float(Wh[lane * NCH + k]);
        bias = __bfloat162float(((const __hip_bfloat16*)bp)[lane]);
    }
    if (!subbias) bias = 0.0f;

    const int niter = (n_rows + nwaves - 1) / nwaves;
    for (int it = 0; it < niter; ++it) {
        const int m = gwave + it * nwaves;
        const bool valid = (m < n_rows);
        if (valid) {
            float x = f32 ? ((const float*)inp)[m * NCH + lane]
                          : __bfloat162float(((const __hip_bfloat16*)inp)[m * NCH + lane]);
            slot[lane] = x;
        }
        __syncthreads();
        if (valid) {
            float a0 = 0.0f, a1 = 0.0f, a2 = 0.0f, a3 = 0.0f;
            const float4* r4 = (const float4*)slot;
            #pragma unroll
            for (int q = 0; q < 16; ++q) {
                float4 rv = r4[q];
                a0 = fmaf(rv.x, w[4 * q + 0], a0);
                a1 = fmaf(rv.y, w[4 * q + 1], a1);
                a2 = fmaf(rv.z, w[4 * q + 2], a2);
                a3 = fmaf(rv.w, w[4 * q + 3], a3);
            }
            outp[m * NCH + lane] = (a0 + a1) + (a2 + a3) - bias;
        }
        __syncthreads();
    }
}

// One wave per node (grid-stride), lane = channel.
// v = relu(P[s][lane] - Q'[n][lane]); max/sum in registers; one store.
// Run boundaries after scatter: start = (n ? offs[n-1] : 0), end = offs[n].
__global__ void node_kernel(const float* __restrict__ P, const float* __restrict__ Qb,
                            const unsigned* __restrict__ sorted_src,
                            const unsigned* __restrict__ offs,
                            const unsigned* __restrict__ flags,
                            void* __restrict__ outp, int n_nodes) {
    const unsigned f32 = flags[0];
    const int lane = threadIdx.x & 63;
    const int gwave = (blockIdx.x * blockDim.x + threadIdx.x) >> 6;
    const int nwaves = (gridDim.x * blockDim.x) >> 6;

    for (int n = gwave; n < n_nodes; n += nwaves) {
        const float q = Qb[n * NCH + lane];
        const int start = (n == 0) ? 0 : (int)offs[n - 1];
        const int end = (int)offs[n];
        float vmax = 0.0f, vsum = 0.0f;
        int sNext = (start < end) ? (int)sorted_src[start] : 0;
        for (int j = start; j < end; ++j) {
            const int s = sNext;
            if (j + 1 < end) sNext = (int)sorted_src[j + 1];   // prefetch next id
            const float p = P[s * NCH + lane];
            const float v = fmaxf(p - q, 0.0f);
            vmax = fmaxf(vmax, v);
            vsum += v;
        }
        const int deg = end - start;
        const float avg = vsum / (float)(deg > 0 ? deg : 1);
        if (f32) {
            float* out = (float*)outp;
            out[n * 2 * NCH + lane] = vmax;
            out[n * 2 * NCH + NCH + lane] = avg;
        } else {
            __hip_bfloat16* out = (__hip_bfloat16*)outp;
            out[n * 2 * NCH + lane] = __float2bfloat16(vmax);
            out[n * 2 * NCH + NCH + lane] = __float2bfloat16(avg);
        }
    }
}

extern "C" void kernel_launch(void* const* d_in, const int* in_sizes, int n_in,
                              void* d_out, int out_size, void* d_ws, size_t ws_size,
                              hipStream_t stream) {
    const void* G = d_in[0];
    const void* RSC = d_in[1];
    const void* src = d_in[2];
    const void* dst = d_in[3];
    const void* W = d_in[4];
    const void* b = d_in[5];

    const int n_nodes = in_sizes[0] / NCH;
    const int n_edges = in_sizes[2];

    // ws layout (bytes):
    //  [flags 256][sorted_src/cnt 4E][offs 4(N+1) pad16][P 4*64N][Q' 4*64N]
    // cnt is only live hist->scan; sorted_src only scatter->node: share region.
    char* ws = (char*)d_ws;
    unsigned* flags = (unsigned*)ws;
    size_t off = 256;
    unsigned* cnt = (unsigned*)(ws + off);          // also sorted_src
    unsigned* sorted_src = cnt;
    off += (size_t)n_edges * 4;
    unsigned* offs = (unsigned*)(ws + off);
    off += (((size_t)(n_nodes + 1) * 4 + 15) / 16) * 16;
    float* P = (float*)(ws + off);
    off += (size_t)n_nodes * NCH * 4;
    float* Qb = (float*)(ws + off);

    const int n_g_probe = (in_sizes[0] < 8192) ? in_sizes[0] : 8192;
    const int n_idx_probe = (n_edges < 8192) ? n_edges : 8192;
    detect_kernel<<<1, 1024, 0, stream>>>((const unsigned short*)G, n_g_probe,
                                          (const unsigned*)src, n_idx_probe, flags);

    init_kernel<<<(n_nodes + 255) / 256, 256, 0, stream>>>(cnt, n_nodes);
    hist_kernel<<<1024, 256, 0, stream>>>(dst, cnt, flags, n_edges);
    scan_kernel<<<1, 1024, 0, stream>>>(cnt, offs, n_nodes);
    // NOTE: scatter overwrites cnt region with sorted_src — cnt is dead after scan.
    scatter_kernel<<<1024, 256, 0, stream>>>(src, dst, offs, sorted_src, flags, n_edges);

    gemm_kernel<<<1024, 256, 0, stream>>>(G, W, b, P, flags, n_nodes, 0);
    gemm_kernel<<<1024, 256, 0, stream>>>(RSC, W, b, Qb, flags, n_nodes, 1);

    node_kernel<<<2048, 256, 0, stream>>>(P, Qb, sorted_src, offs, flags, d_out, n_nodes);
}

// Round 3
// 288.975 us; speedup vs baseline: 2.1416x; 1.3007x over previous
//
#include <hip/hip_runtime.h>
#include <hip/hip_bf16.h>

#define NCH 64

// ---------------------------------------------------------------------------
// Block 0: dtype detection (flags[0]=fp32?, flags[1]=int64?).
// Other blocks: zero the degree-count array (ws is poisoned 0xAA each call).
// ---------------------------------------------------------------------------
__global__ void detect_init_kernel(const unsigned short* __restrict__ gp, int n16,
                                   const unsigned* __restrict__ ip, int niw,
                                   unsigned* __restrict__ flags,
                                   unsigned* __restrict__ cnt, int n_nodes) {
    if (blockIdx.x == 0) {
        __shared__ unsigned se, so;
        if (threadIdx.x == 0) { se = 0u; so = 0u; }
        __syncthreads();
        unsigned le = 0u, lo = 0u;
        // fp32 data viewed as shorts: ~12.5% have "bf16 exponent" >= 0xC0
        // (|x|>=2^65). Genuine bf16 N(0,1): none.
        for (int i = threadIdx.x; i < n16; i += blockDim.x) {
            unsigned ex = (unsigned)((gp[i] >> 7) & 0xFFu);
            if (ex >= 0xC0u) le++;
        }
        // int64 ids (<2^31): every odd 32-bit word is 0. int32 ids: not.
        for (int i = threadIdx.x; i < niw; i += blockDim.x) {
            if ((i & 1) && ip[i] != 0u) lo++;
        }
        atomicAdd(&se, le);
        atomicAdd(&so, lo);
        __syncthreads();
        if (threadIdx.x == 0) {
            flags[0] = (se > 50u) ? 1u : 0u;
            flags[1] = (so < 50u) ? 1u : 0u;
        }
    } else {
        const int stride = (gridDim.x - 1) * blockDim.x;
        for (int i = (blockIdx.x - 1) * blockDim.x + threadIdx.x; i < n_nodes; i += stride)
            cnt[i] = 0u;
    }
}

// Histogram of dst.
__global__ void hist_kernel(const void* __restrict__ dstp, unsigned* __restrict__ cnt,
                            const unsigned* __restrict__ flags, int n_edges) {
    const unsigned i64 = flags[1];
    const int stride = gridDim.x * blockDim.x;
    for (int e = blockIdx.x * blockDim.x + threadIdx.x; e < n_edges; e += stride) {
        int d = i64 ? (int)((const long long*)dstp)[e] : ((const int*)dstp)[e];
        atomicAdd(&cnt[d], 1u);
    }
}

// ---------------------------------------------------------------------------
// Multi-block exclusive scan, 3 phases. Phase A: per-block 256-wide scan,
// write in-block exclusive prefix + per-block total. Phase B: single block
// scans the (<=1024) block totals. Phase C: add block offsets.
// ---------------------------------------------------------------------------
__global__ void scanA_kernel(const unsigned* __restrict__ cnt, unsigned* __restrict__ offs,
                             unsigned* __restrict__ bsum, int n) {
    __shared__ unsigned s[256];
    const int t = threadIdx.x;
    const int i = blockIdx.x * 256 + t;
    unsigned v = (i < n) ? cnt[i] : 0u;
    s[t] = v;
    __syncthreads();
    #pragma unroll
    for (int off = 1; off < 256; off <<= 1) {
        unsigned u = (t >= off) ? s[t - off] : 0u;
        __syncthreads();
        s[t] += u;
        __syncthreads();
    }
    if (i < n) offs[i] = s[t] - v;          // exclusive within block
    if (t == 255) bsum[blockIdx.x] = s[255];
}

__global__ void scanB_kernel(unsigned* __restrict__ bsum, int nb) {
    __shared__ unsigned s[1024];
    const int t = threadIdx.x;
    unsigned v = (t < nb) ? bsum[t] : 0u;
    s[t] = v;
    __syncthreads();
    #pragma unroll
    for (int off = 1; off < 1024; off <<= 1) {
        unsigned u = (t >= off) ? s[t - off] : 0u;
        __syncthreads();
        s[t] += u;
        __syncthreads();
    }
    if (t < nb) bsum[t] = s[t] - v;         // exclusive block offsets
}

__global__ void scanC_kernel(unsigned* __restrict__ offs, const unsigned* __restrict__ bsum,
                             int n) {
    const int i = blockIdx.x * 256 + threadIdx.x;
    if (i < n) offs[i] += bsum[blockIdx.x];
}

// Scatter src ids into dst-sorted order. offs doubles as the cursor array:
// afterwards offs[d] == end-of-run(d).
__global__ void scatter_kernel(const void* __restrict__ srcp, const void* __restrict__ dstp,
                               unsigned* __restrict__ offs, unsigned* __restrict__ sorted_src,
                               const unsigned* __restrict__ flags, int n_edges) {
    const unsigned i64 = flags[1];
    const int stride = gridDim.x * blockDim.x;
    for (int e = blockIdx.x * blockDim.x + threadIdx.x; e < n_edges; e += stride) {
        int s, d;
        if (i64) {
            s = (int)((const long long*)srcp)[e];
            d = (int)((const long long*)dstp)[e];
        } else {
            s = ((const int*)srcp)[e];
            d = ((const int*)dstp)[e];
        }
        unsigned pos = atomicAdd(&offs[d], 1u);
        sorted_src[pos] = (unsigned)s;
    }
}

// ---------------------------------------------------------------------------
// Fused GEMM: rows 0..N-1 -> P = G @ W^T ; rows N..2N-1 -> Q' = RSC @ W^T - b.
// P and Q' are contiguous in PQ. Wave per row, lane = out channel, W row in
// VGPRs, input row broadcast via per-wave LDS slot.
// ---------------------------------------------------------------------------
__global__ void gemm2_kernel(const void* __restrict__ Gp, const void* __restrict__ Rp,
                             const void* __restrict__ Wp, const void* __restrict__ bp,
                             float* __restrict__ PQ,
                             const unsigned* __restrict__ flags, int n_nodes) {
    const unsigned f32 = flags[0];
    const int lane = threadIdx.x & 63;
    const int waveInBlk = threadIdx.x >> 6;
    const int wavesPerBlk = blockDim.x >> 6;
    const int gwave = blockIdx.x * wavesPerBlk + waveInBlk;
    const int nwaves = gridDim.x * wavesPerBlk;
    const int n_rows = 2 * n_nodes;

    __shared__ float lds[4 * NCH];
    float* slot = &lds[waveInBlk * NCH];

    float w[NCH];
    float bias;
    if (f32) {
        const float* Wf = (const float*)Wp;
        #pragma unroll
        for (int k = 0; k < NCH; ++k) w[k] = Wf[lane * NCH + k];
        bias = ((const float*)bp)[lane];
    } else {
        const __hip_bfloat16* Wh = (const __hip_bfloat16*)Wp;
        #pragma unroll
        for (int k = 0; k < NCH; ++k) w[k] = __bfloat162float(Wh[lane * NCH + k]);
        bias = __bfloat162float(((const __hip_bfloat16*)bp)[lane]);
    }

    const int niter = (n_rows + nwaves - 1) / nwaves;
    for (int it = 0; it < niter; ++it) {
        const int m = gwave + it * nwaves;
        const bool valid = (m < n_rows);
        bool isQ = false;
        if (valid) {
            int r = m;
            const void* inp = Gp;
            if (m >= n_nodes) { r = m - n_nodes; inp = Rp; isQ = true; }
            float x = f32 ? ((const float*)inp)[r * NCH + lane]
                          : __bfloat162float(((const __hip_bfloat16*)inp)[r * NCH + lane]);
            slot[lane] = x;
        }
        __syncthreads();
        if (valid) {
            float a0 = 0.0f, a1 = 0.0f, a2 = 0.0f, a3 = 0.0f;
            const float4* r4 = (const float4*)slot;
            #pragma unroll
            for (int q = 0; q < 16; ++q) {
                float4 rv = r4[q];
                a0 = fmaf(rv.x, w[4 * q + 0], a0);
                a1 = fmaf(rv.y, w[4 * q + 1], a1);
                a2 = fmaf(rv.z, w[4 * q + 2], a2);
                a3 = fmaf(rv.w, w[4 * q + 3], a3);
            }
            float acc = (a0 + a1) + (a2 + a3);
            if (isQ) acc -= bias;
            PQ[m * NCH + lane] = acc;
        }
        __syncthreads();
    }
}

// One wave per node (grid-stride), lane = channel.
// v = relu(P[s][lane] - Q'[n][lane]); max/sum in registers; one store.
__global__ void node_kernel(const float* __restrict__ PQ,
                            const unsigned* __restrict__ sorted_src,
                            const unsigned* __restrict__ offs,
                            const unsigned* __restrict__ flags,
                            void* __restrict__ outp, int n_nodes) {
    const unsigned f32 = flags[0];
    const int lane = threadIdx.x & 63;
    const int gwave = (blockIdx.x * blockDim.x + threadIdx.x) >> 6;
    const int nwaves = (gridDim.x * blockDim.x) >> 6;
    const float* P = PQ;
    const float* Qb = PQ + (size_t)n_nodes * NCH;

    for (int n = gwave; n < n_nodes; n += nwaves) {
        const float q = Qb[n * NCH + lane];
        const int start = (n == 0) ? 0 : (int)offs[n - 1];
        const int end = (int)offs[n];
        float vmax = 0.0f, vsum = 0.0f;
        int sNext = (start < end) ? (int)sorted_src[start] : 0;
        for (int j = start; j < end; ++j) {
            const int s = sNext;
            if (j + 1 < end) sNext = (int)sorted_src[j + 1];   // prefetch next id
            const float p = P[s * NCH + lane];
            const float v = fmaxf(p - q, 0.0f);
            vmax = fmaxf(vmax, v);
            vsum += v;
        }
        const int deg = end - start;
        const float avg = vsum / (float)(deg > 0 ? deg : 1);
        if (f32) {
            float* out = (float*)outp;
            out[n * 2 * NCH + lane] = vmax;
            out[n * 2 * NCH + NCH + lane] = avg;
        } else {
            __hip_bfloat16* out = (__hip_bfloat16*)outp;
            out[n * 2 * NCH + lane] = __float2bfloat16(vmax);
            out[n * 2 * NCH + NCH + lane] = __float2bfloat16(avg);
        }
    }
}

extern "C" void kernel_launch(void* const* d_in, const int* in_sizes, int n_in,
                              void* d_out, int out_size, void* d_ws, size_t ws_size,
                              hipStream_t stream) {
    const void* G = d_in[0];
    const void* RSC = d_in[1];
    const void* src = d_in[2];
    const void* dst = d_in[3];
    const void* W = d_in[4];
    const void* b = d_in[5];

    const int n_nodes = in_sizes[0] / NCH;
    const int n_edges = in_sizes[2];

    // ws layout (bytes):
    //  [flags 256][sorted_src/cnt 4E][offs 4N pad][bsum 4*1024 pad][PQ 4*64*2N]
    char* ws = (char*)d_ws;
    unsigned* flags = (unsigned*)ws;
    size_t off = 256;
    unsigned* cnt = (unsigned*)(ws + off);          // also sorted_src
    unsigned* sorted_src = cnt;
    off += (size_t)n_edges * 4;
    unsigned* offs = (unsigned*)(ws + off);
    off += (((size_t)n_nodes * 4 + 255) / 256) * 256;
    unsigned* bsum = (unsigned*)(ws + off);
    off += 4096;
    float* PQ = (float*)(ws + off);

    const int n_g_probe = (in_sizes[0] < 8192) ? in_sizes[0] : 8192;
    const int n_idx_probe = (n_edges < 8192) ? n_edges : 8192;

    detect_init_kernel<<<64, 256, 0, stream>>>((const unsigned short*)G, n_g_probe,
                                               (const unsigned*)src, n_idx_probe,
                                               flags, cnt, n_nodes);
    hist_kernel<<<1024, 256, 0, stream>>>(dst, cnt, flags, n_edges);

    const int nb = (n_nodes + 255) / 256;           // <= 1024 (n_nodes <= 262144)
    scanA_kernel<<<nb, 256, 0, stream>>>(cnt, offs, bsum, n_nodes);
    scanB_kernel<<<1, 1024, 0, stream>>>(bsum, nb);
    scanC_kernel<<<nb, 256, 0, stream>>>(offs, bsum, n_nodes);

    scatter_kernel<<<1024, 256, 0, stream>>>(src, dst, offs, sorted_src, flags, n_edges);

    gemm2_kernel<<<2048, 256, 0, stream>>>(G, RSC, W, b, PQ, flags, n_nodes);

    node_kernel<<<2048, 256, 0, stream>>>(PQ, sorted_src, offs, flags, d_out, n_nodes);
}

// Round 4
// 266.359 us; speedup vs baseline: 2.3235x; 1.0849x over previous
//
#include <hip/hip_runtime.h>
#include <hip/hip_bf16.h>

#define NCH 64

// ---------------------------------------------------------------------------
// Block 0: dtype detection (flags[0]=fp32?, flags[1]=int64?).
// Other blocks: zero the degree-count array (ws is poisoned 0xAA each call).
// ---------------------------------------------------------------------------
__global__ void detect_init_kernel(const unsigned short* __restrict__ gp, int n16,
                                   const unsigned* __restrict__ ip, int niw,
                                   unsigned* __restrict__ flags,
                                   unsigned* __restrict__ cnt, int n_nodes) {
    if (blockIdx.x == 0) {
        __shared__ unsigned se, so;
        if (threadIdx.x == 0) { se = 0u; so = 0u; }
        __syncthreads();
        unsigned le = 0u, lo = 0u;
        // fp32 viewed as shorts: ~12.5% show "bf16 exponent" >= 0xC0 (|x|>=2^65).
        // Genuine bf16 N(0,1): none.
        for (int i = threadIdx.x; i < n16; i += blockDim.x) {
            unsigned ex = (unsigned)((gp[i] >> 7) & 0xFFu);
            if (ex >= 0xC0u) le++;
        }
        // int64 ids (<2^31): every odd 32-bit word is 0. int32 ids: not.
        for (int i = threadIdx.x; i < niw; i += blockDim.x) {
            if ((i & 1) && ip[i] != 0u) lo++;
        }
        atomicAdd(&se, le);
        atomicAdd(&so, lo);
        __syncthreads();
        if (threadIdx.x == 0) {
            flags[0] = (se > 50u) ? 1u : 0u;
            flags[1] = (so < 50u) ? 1u : 0u;
        }
    } else {
        const int stride = (gridDim.x - 1) * blockDim.x;
        for (int i = (blockIdx.x - 1) * blockDim.x + threadIdx.x; i < n_nodes; i += stride)
            cnt[i] = 0u;
    }
}

// Histogram of dst.
__global__ void hist_kernel(const void* __restrict__ dstp, unsigned* __restrict__ cnt,
                            const unsigned* __restrict__ flags, int n_edges) {
    const unsigned i64 = flags[1];
    const int stride = gridDim.x * blockDim.x;
    for (int e = blockIdx.x * blockDim.x + threadIdx.x; e < n_edges; e += stride) {
        int d = i64 ? (int)((const long long*)dstp)[e] : ((const int*)dstp)[e];
        atomicAdd(&cnt[d], 1u);
    }
}

// ---------------------------------------------------------------------------
// Multi-block exclusive scan, 2 phases.
// A: per-block 256-wide scan -> in-block exclusive prefix + per-block total.
// BC: each block reduces bsum[0..blockIdx.x) and adds to its 256 offs.
// ---------------------------------------------------------------------------
__global__ void scanA_kernel(const unsigned* __restrict__ cnt, unsigned* __restrict__ offs,
                             unsigned* __restrict__ bsum, int n) {
    __shared__ unsigned s[256];
    const int t = threadIdx.x;
    const int i = blockIdx.x * 256 + t;
    unsigned v = (i < n) ? cnt[i] : 0u;
    s[t] = v;
    __syncthreads();
    #pragma unroll
    for (int off = 1; off < 256; off <<= 1) {
        unsigned u = (t >= off) ? s[t - off] : 0u;
        __syncthreads();
        s[t] += u;
        __syncthreads();
    }
    if (i < n) offs[i] = s[t] - v;          // exclusive within block
    if (t == 255) bsum[blockIdx.x] = s[255];
}

__global__ void scanBC_kernel(unsigned* __restrict__ offs, const unsigned* __restrict__ bsum,
                              int n) {
    __shared__ unsigned red[256];
    const int t = threadIdx.x;
    unsigned part = 0u;
    for (int i = t; i < (int)blockIdx.x; i += 256) part += bsum[i];
    red[t] = part;
    __syncthreads();
    #pragma unroll
    for (int off = 128; off > 0; off >>= 1) {
        if (t < off) red[t] += red[t + off];
        __syncthreads();
    }
    const int i = blockIdx.x * 256 + t;
    if (i < n) offs[i] += red[0];
}

// Scatter src ids into dst-sorted order. offs doubles as the cursor array:
// afterwards offs[d] == end-of-run(d).
__global__ void scatter_kernel(const void* __restrict__ srcp, const void* __restrict__ dstp,
                               unsigned* __restrict__ offs, unsigned* __restrict__ sorted_src,
                               const unsigned* __restrict__ flags, int n_edges) {
    const unsigned i64 = flags[1];
    const int stride = gridDim.x * blockDim.x;
    for (int e = blockIdx.x * blockDim.x + threadIdx.x; e < n_edges; e += stride) {
        int s, d;
        if (i64) {
            s = (int)((const long long*)srcp)[e];
            d = (int)((const long long*)dstp)[e];
        } else {
            s = ((const int*)srcp)[e];
            d = ((const int*)dstp)[e];
        }
        unsigned pos = atomicAdd(&offs[d], 1u);
        sorted_src[pos] = (unsigned)s;
    }
}

// ---------------------------------------------------------------------------
// Fused GEMM: rows 0..N-1 -> P = G @ W^T ; rows N..2N-1 -> Q' = RSC @ W^T - b.
// 4 rows per wave-iteration: lane loads ushort4/float4 (row m0+(lane>>4),
// cols (lane&15)*4..+3) into the wave's 256-float LDS slot; each lane then
// computes output channel `lane` for all 4 rows. Output stored in PQ with
// the INPUT dtype (bf16 when inputs are bf16 -> halves node-kernel fetch).
// ---------------------------------------------------------------------------
__global__ void gemm2_kernel(const void* __restrict__ Gp, const void* __restrict__ Rp,
                             const void* __restrict__ Wp, const void* __restrict__ bp,
                             void* __restrict__ PQ,
                             const unsigned* __restrict__ flags, int n_nodes) {
    const unsigned f32 = flags[0];
    const int lane = threadIdx.x & 63;
    const int waveInBlk = threadIdx.x >> 6;
    const int wavesPerBlk = blockDim.x >> 6;
    const int gwave = blockIdx.x * wavesPerBlk + waveInBlk;
    const int nwaves = gridDim.x * wavesPerBlk;
    const int n_rows = 2 * n_nodes;
    const int ngroups = (n_rows + 3) / 4;

    __shared__ float lds[4 * 4 * NCH];           // 4 waves x 4 rows x 64
    float* slot = &lds[waveInBlk * 4 * NCH];

    float w[NCH];
    float bias;
    if (f32) {
        const float* Wf = (const float*)Wp;
        #pragma unroll
        for (int k = 0; k < NCH; ++k) w[k] = Wf[lane * NCH + k];
        bias = ((const float*)bp)[lane];
    } else {
        const __hip_bfloat16* Wh = (const __hip_bfloat16*)Wp;
        #pragma unroll
        for (int k = 0; k < NCH; ++k) w[k] = __bfloat162float(Wh[lane * NCH + k]);
        bias = __bfloat162float(((const __hip_bfloat16*)bp)[lane]);
    }

    const int niter = (ngroups + nwaves - 1) / nwaves;
    for (int it = 0; it < niter; ++it) {
        const int grp = gwave + it * nwaves;
        const bool gvalid = (grp < ngroups);
        const int m0 = grp * 4;
        if (gvalid) {
            const int myrow = m0 + (lane >> 4);           // row this lane loads
            const int col = (lane & 15) * 4;
            float x0 = 0.f, x1 = 0.f, x2 = 0.f, x3 = 0.f;
            if (myrow < n_rows) {
                const bool isQ = (myrow >= n_nodes);
                const int r = isQ ? (myrow - n_nodes) : myrow;
                const void* inp = isQ ? Rp : Gp;
                if (f32) {
                    float4 v = *(const float4*)((const float*)inp + (size_t)r * NCH + col);
                    x0 = v.x; x1 = v.y; x2 = v.z; x3 = v.w;
                } else {
                    ushort4 v = *(const ushort4*)((const unsigned short*)inp +
                                                  (size_t)r * NCH + col);
                    x0 = __bfloat162float(*(__hip_bfloat16*)&v.x);
                    x1 = __bfloat162float(*(__hip_bfloat16*)&v.y);
                    x2 = __bfloat162float(*(__hip_bfloat16*)&v.z);
                    x3 = __bfloat162float(*(__hip_bfloat16*)&v.w);
                }
            }
            const int sb = (lane >> 4) * NCH + col;
            slot[sb + 0] = x0; slot[sb + 1] = x1; slot[sb + 2] = x2; slot[sb + 3] = x3;
        }
        __syncthreads();
        if (gvalid) {
            #pragma unroll
            for (int rr = 0; rr < 4; ++rr) {
                const int m = m0 + rr;
                if (m < n_rows) {
                    float a0 = 0.f, a1 = 0.f, a2 = 0.f, a3 = 0.f;
                    const float4* r4 = (const float4*)(slot + rr * NCH);
                    #pragma unroll
                    for (int q = 0; q < 16; ++q) {
                        float4 rv = r4[q];
                        a0 = fmaf(rv.x, w[4 * q + 0], a0);
                        a1 = fmaf(rv.y, w[4 * q + 1], a1);
                        a2 = fmaf(rv.z, w[4 * q + 2], a2);
                        a3 = fmaf(rv.w, w[4 * q + 3], a3);
                    }
                    float acc = (a0 + a1) + (a2 + a3);
                    if (m >= n_nodes) acc -= bias;         // Q' rows
                    if (f32) ((float*)PQ)[(size_t)m * NCH + lane] = acc;
                    else ((__hip_bfloat16*)PQ)[(size_t)m * NCH + lane] =
                             __float2bfloat16(acc);
                }
            }
        }
        __syncthreads();
    }
}

// ---------------------------------------------------------------------------
// One wave per node (grid-stride), lane = channel.
// v = relu(P[s][lane] - Q'[n][lane]); max/sum in registers; one store.
// Edge loop unrolled x4 -> 4 gather loads in flight per wave (latency hiding).
// ---------------------------------------------------------------------------
__global__ void node_kernel(const void* __restrict__ PQ,
                            const unsigned* __restrict__ sorted_src,
                            const unsigned* __restrict__ offs,
                            const unsigned* __restrict__ flags,
                            void* __restrict__ outp, int n_nodes) {
    const unsigned f32 = flags[0];
    const int lane = threadIdx.x & 63;
    const int gwave = (blockIdx.x * blockDim.x + threadIdx.x) >> 6;
    const int nwaves = (gridDim.x * blockDim.x) >> 6;
    const float* Pf = (const float*)PQ;
    const unsigned short* Ph = (const unsigned short*)PQ;

    for (int n = gwave; n < n_nodes; n += nwaves) {
        float q;
        if (f32) q = Pf[(size_t)(n_nodes + n) * NCH + lane];
        else {
            unsigned short h = Ph[(size_t)(n_nodes + n) * NCH + lane];
            q = __bfloat162float(*(__hip_bfloat16*)&h);
        }
        const int start = (n == 0) ? 0 : (int)offs[n - 1];
        const int end = (int)offs[n];
        float vmax = 0.0f, vsum = 0.0f;
        int j = start;
        for (; j + 4 <= end; j += 4) {
            const int s0 = (int)sorted_src[j];
            const int s1 = (int)sorted_src[j + 1];
            const int s2 = (int)sorted_src[j + 2];
            const int s3 = (int)sorted_src[j + 3];
            float p0, p1, p2, p3;
            if (f32) {
                p0 = Pf[(size_t)s0 * NCH + lane];
                p1 = Pf[(size_t)s1 * NCH + lane];
                p2 = Pf[(size_t)s2 * NCH + lane];
                p3 = Pf[(size_t)s3 * NCH + lane];
            } else {
                unsigned short h0 = Ph[(size_t)s0 * NCH + lane];
                unsigned short h1 = Ph[(size_t)s1 * NCH + lane];
                unsigned short h2 = Ph[(size_t)s2 * NCH + lane];
                unsigned short h3 = Ph[(size_t)s3 * NCH + lane];
                p0 = __bfloat162float(*(__hip_bfloat16*)&h0);
                p1 = __bfloat162float(*(__hip_bfloat16*)&h1);
                p2 = __bfloat162float(*(__hip_bfloat16*)&h2);
                p3 = __bfloat162float(*(__hip_bfloat16*)&h3);
            }
            const float v0 = fmaxf(p0 - q, 0.0f);
            const float v1 = fmaxf(p1 - q, 0.0f);
            const float v2 = fmaxf(p2 - q, 0.0f);
            const float v3 = fmaxf(p3 - q, 0.0f);
            vmax = fmaxf(fmaxf(vmax, v0), fmaxf(v1, fmaxf(v2, v3)));
            vsum += (v0 + v1) + (v2 + v3);
        }
        for (; j < end; ++j) {
            const int s = (int)sorted_src[j];
            float p;
            if (f32) p = Pf[(size_t)s * NCH + lane];
            else {
                unsigned short h = Ph[(size_t)s * NCH + lane];
                p = __bfloat162float(*(__hip_bfloat16*)&h);
            }
            const float v = fmaxf(p - q, 0.0f);
            vmax = fmaxf(vmax, v);
            vsum += v;
        }
        const int deg = end - start;
        const float avg = vsum / (float)(deg > 0 ? deg : 1);
        if (f32) {
            float* out = (float*)outp;
            out[(size_t)n * 2 * NCH + lane] = vmax;
            out[(size_t)n * 2 * NCH + NCH + lane] = avg;
        } else {
            __hip_bfloat16* out = (__hip_bfloat16*)outp;
            out[(size_t)n * 2 * NCH + lane] = __float2bfloat16(vmax);
            out[(size_t)n * 2 * NCH + NCH + lane] = __float2bfloat16(avg);
        }
    }
}

extern "C" void kernel_launch(void* const* d_in, const int* in_sizes, int n_in,
                              void* d_out, int out_size, void* d_ws, size_t ws_size,
                              hipStream_t stream) {
    const void* G = d_in[0];
    const void* RSC = d_in[1];
    const void* src = d_in[2];
    const void* dst = d_in[3];
    const void* W = d_in[4];
    const void* b = d_in[5];

    const int n_nodes = in_sizes[0] / NCH;
    const int n_edges = in_sizes[2];

    // ws layout (bytes):
    //  [flags 256][sorted_src/cnt 4E][offs 4N pad][bsum 4*1024 pad][PQ dtype*64*2N]
    char* ws = (char*)d_ws;
    unsigned* flags = (unsigned*)ws;
    size_t off = 256;
    unsigned* cnt = (unsigned*)(ws + off);          // also sorted_src
    unsigned* sorted_src = cnt;
    off += (size_t)n_edges * 4;
    unsigned* offs = (unsigned*)(ws + off);
    off += (((size_t)n_nodes * 4 + 255) / 256) * 256;
    unsigned* bsum = (unsigned*)(ws + off);
    off += 4096;
    void* PQ = (void*)(ws + off);                   // fp32 or bf16 per flags[0]

    const int n_g_probe = (in_sizes[0] < 8192) ? in_sizes[0] : 8192;
    const int n_idx_probe = (n_edges < 8192) ? n_edges : 8192;

    detect_init_kernel<<<64, 256, 0, stream>>>((const unsigned short*)G, n_g_probe,
                                               (const unsigned*)src, n_idx_probe,
                                               flags, cnt, n_nodes);
    hist_kernel<<<1024, 256, 0, stream>>>(dst, cnt, flags, n_edges);

    const int nb = (n_nodes + 255) / 256;           // <= 1024
    scanA_kernel<<<nb, 256, 0, stream>>>(cnt, offs, bsum, n_nodes);
    scanBC_kernel<<<nb, 256, 0, stream>>>(offs, bsum, n_nodes);

    scatter_kernel<<<1024, 256, 0, stream>>>(src, dst, offs, sorted_src, flags, n_edges);

    gemm2_kernel<<<2048, 256, 0, stream>>>(G, RSC, W, b, PQ, flags, n_nodes);

    node_kernel<<<2048, 256, 0, stream>>>(PQ, sorted_src, offs, flags, d_out, n_nodes);
}